// Round 1
// baseline (2601.496 us; speedup 1.0000x reference)
//
#include <hip/hip_runtime.h>
#include <math.h>

// Problem constants
#define B 8
#define C 64
#define HW 96
#define NV 36864   // per-variant weight count: 64ci * 9 * 64co

// ---------------- prep: fuse BN into weights/bias, build rotated/permuted variants ----------------

// tap rotation map: effective kernel for branch-rotation k is K'[i,j] = r^k(K)[i,j],
// r(K)[i,j] = K[2-j, i]
__device__ __forceinline__ void rotmap(int k, int ta, int tb, int& sa, int& sb) {
    switch (k) {
        case 0: sa = ta;     sb = tb;     break;
        case 1: sa = 2 - tb; sb = ta;     break;
        case 2: sa = 2 - ta; sb = 2 - tb; break;
        default: sa = tb;    sb = 2 - ta; break;
    }
}

// layout of prepared weights: Wg[variant][ci][tap(9)][co]  (co contiguous)
__global__ void prep_w(const float* __restrict__ dcn_w, const float* __restrict__ c2w,
                       const float* __restrict__ c3w,
                       const float* __restrict__ gamma, const float* __restrict__ var,
                       float* __restrict__ W1g, float* __restrict__ W2g, float* __restrict__ W3g) {
    int idx = blockIdx.x * 256 + threadIdx.x;
    if (idx >= 16 * NV) return;
    int region = idx / NV;     // 0..7 -> W1 branch i; 8..11 -> W2 rot k; 12..15 -> W3 rot k
    int rem = idx % NV;
    int ci = rem / 576;        // 576 = 9*64
    int r2 = rem % 576;
    int t  = r2 >> 6;          // 0..8
    int co = r2 & 63;
    int ta = t / 3, tb = t % 3;

    const float* src; float* dst; int k, srcci, l;
    if (region < 8) {
        int i = region;
        k = i & 3;
        srcci = (ci + 8 * i) & 63;   // fold channel roll into conv1 weights
        src = dcn_w; dst = W1g + i * NV; l = 0;
    } else if (region < 12) {
        k = region - 8; srcci = ci; src = c2w; dst = W2g + k * NV; l = 1;
    } else {
        k = region - 12; srcci = ci; src = c3w; dst = W3g + k * NV; l = 2;
    }
    int sa, sb;
    rotmap(k, ta, tb, sa, sb);
    float s = gamma[l * 64 + co] * rsqrtf(var[l * 64 + co] + 1e-5f);
    dst[rem] = src[((co * 64 + srcci) * 3 + sa) * 3 + sb] * s;
}

__global__ void prep_bias(const float* __restrict__ dcn_b, const float* __restrict__ c2b,
                          const float* __restrict__ c3b,
                          const float* __restrict__ gamma, const float* __restrict__ beta,
                          const float* __restrict__ mean, const float* __restrict__ var,
                          float* __restrict__ biasg) {
    int t = threadIdx.x;
    if (t < 192) {
        int l = t >> 6, c = t & 63;
        const float* cb = (l == 0) ? dcn_b : ((l == 1) ? c2b : c3b);
        float s = gamma[l * 64 + c] * rsqrtf(var[l * 64 + c] + 1e-5f);
        biasg[t] = cb[c] * s + beta[l * 64 + c] - mean[l * 64 + c] * s;
    }
}

// ---------------- generic 3x3 conv, 64->64 ch, fused bias+relu ----------------
// Output tile 8 rows x 16 cols x 64 out-ch per block (256 threads).
// Thread: 4 consecutive x-pixels x 8 out-channels (32 accumulators).
// input coord = out coord + shift + (tap-1)*DIL ; out-of-range input reads as 0.
// MODE 0: store relu(conv+bias) to out[b][co][Hout][Wout]
// MODE 1: reduce max over 64 co, then maxbuf[b][oy][ox] = (first? m : max(old,m)); Hout=Wout=96.
template<int DIL, int MODE>
__global__ __launch_bounds__(256) void conv_k(
    const float* __restrict__ in, float* __restrict__ out,
    const float* __restrict__ Wg, const float* __restrict__ bias,
    int Hin, int Win, int Hout, int Wout, int shift, int first) {

    __shared__ float xt[16][12][21];   // 16 ci x 12 rows x 20 cols (+1 pad)
    __shared__ float wt[16 * 9 * 64];  // ci x tap x co
    __shared__ float red[8 * 128];

    int b   = blockIdx.z;
    int oy0 = blockIdx.y * 8;
    int ox0 = blockIdx.x * 16;
    int t   = threadIdx.x;
    int cog = t >> 5;               // 0..7  (8 out-channels each)
    int pg  = t & 31;               // 32 pixel groups
    int prow  = pg >> 2;            // 0..7
    int pcol4 = (pg & 3) << 2;      // 0,4,8,12

    float acc[4][8];
#pragma unroll
    for (int p = 0; p < 4; p++)
#pragma unroll
        for (int j = 0; j < 8; j++) acc[p][j] = 0.f;

    const float* inb = in + (size_t)b * 64 * Hin * Win;

    for (int cc = 0; cc < 64; cc += 16) {
        // stage input tile (zero-padded out-of-range)
        for (int e = t; e < 16 * 240; e += 256) {
            int ci = e / 240;
            int r  = e - ci * 240;
            int yy = r / 20;
            int xx = r - yy * 20;
            int gy = oy0 + shift - 2 + yy;
            int gx = ox0 + shift - 2 + xx;
            float v = 0.f;
            if ((unsigned)gy < (unsigned)Hin && (unsigned)gx < (unsigned)Win)
                v = inb[((size_t)(cc + ci) * Hin + gy) * Win + gx];
            xt[ci][yy][xx] = v;
        }
        // stage weights (straight contiguous copy)
        for (int e = t; e < 9216; e += 256) wt[e] = Wg[cc * 576 + e];
        __syncthreads();

        for (int ci = 0; ci < 16; ci++) {
#pragma unroll
            for (int ta = 0; ta < 3; ta++) {
#pragma unroll
                for (int tb = 0; tb < 3; tb++) {
                    int ty_ = prow + ta * DIL - DIL + 2;
                    int txb = pcol4 + tb * DIL - DIL + 2;
                    float xv[4];
#pragma unroll
                    for (int p = 0; p < 4; p++) xv[p] = xt[ci][ty_][txb + p];
                    const float4* wp = (const float4*)&wt[(ci * 9 + ta * 3 + tb) * 64 + (cog << 3)];
                    float4 wa = wp[0], wb = wp[1];
                    float wv[8] = {wa.x, wa.y, wa.z, wa.w, wb.x, wb.y, wb.z, wb.w};
#pragma unroll
                    for (int p = 0; p < 4; p++)
#pragma unroll
                        for (int j = 0; j < 8; j++)
                            acc[p][j] = fmaf(xv[p], wv[j], acc[p][j]);
                }
            }
        }
        __syncthreads();
    }

    float bi[8];
#pragma unroll
    for (int j = 0; j < 8; j++) bi[j] = bias[(cog << 3) + j];

    if (MODE == 0) {
        int oy = oy0 + prow;
        if (oy < Hout) {
#pragma unroll
            for (int p = 0; p < 4; p++) {
                int ox = ox0 + pcol4 + p;
                if (ox < Wout) {
#pragma unroll
                    for (int j = 0; j < 8; j++) {
                        int co = (cog << 3) + j;
                        out[((size_t)(b * 64 + co) * Hout + oy) * Wout + ox] =
                            fmaxf(acc[p][j] + bi[j], 0.f);
                    }
                }
            }
        }
    } else {
        // per-thread max over 8 co, then cross-cog reduce in LDS
#pragma unroll
        for (int p = 0; p < 4; p++) {
            float m = -1e30f;
#pragma unroll
            for (int j = 0; j < 8; j++) m = fmaxf(m, fmaxf(acc[p][j] + bi[j], 0.f));
            red[cog * 128 + prow * 16 + pcol4 + p] = m;
        }
        __syncthreads();
        if (t < 128) {
            int pid = t;
            float m = red[pid];
#pragma unroll
            for (int g = 1; g < 8; g++) m = fmaxf(m, red[g * 128 + pid]);
            int oy = oy0 + (pid >> 4), ox = ox0 + (pid & 15);
            if (oy < Hout && ox < Wout) {
                size_t o = ((size_t)b * 96 + oy) * 96 + ox;
                out[o] = first ? m : fmaxf(out[o], m);
            }
        }
    }
}

__global__ void final_k(const float* __restrict__ maxbuf, float* __restrict__ out) {
    int i = blockIdx.x * 256 + threadIdx.x;
    if (i < B * HW * HW) {
        float v = 1.f / (1.f + expf(-maxbuf[i]));
        out[i] = fminf(fmaxf(v, 1e-4f), 1.f - 1e-4f);
    }
}

// ---------------- launch ----------------

extern "C" void kernel_launch(void* const* d_in, const int* in_sizes, int n_in,
                              void* d_out, int out_size, void* d_ws, size_t ws_size,
                              hipStream_t stream) {
    const float* x     = (const float*)d_in[0];
    // d_in[1] = perms (analytic: channel roll by 8i, folded into W1)
    const float* dcn_w = (const float*)d_in[2];
    const float* dcn_b = (const float*)d_in[3];
    const float* c2w   = (const float*)d_in[4];
    const float* c2b   = (const float*)d_in[5];
    const float* c3w   = (const float*)d_in[6];
    const float* c3b   = (const float*)d_in[7];
    const float* gamma = (const float*)d_in[8];
    const float* beta  = (const float*)d_in[9];
    const float* mean  = (const float*)d_in[10];
    const float* var   = (const float*)d_in[11];

    float* ws = (float*)d_ws;
    float* W1g    = ws;                          // 8*NV
    float* W2g    = W1g + 8 * NV;                // 4*NV
    float* W3g    = W2g + 4 * NV;                // 4*NV
    float* biasg  = W3g + 4 * NV;                // 192
    float* maxbuf = biasg + 192;                 // 8*96*96
    float* buf1   = maxbuf + B * HW * HW;        // 8*64*104*104
    float* buf2   = buf1 + (size_t)B * 64 * 104 * 104;

    prep_w<<<(16 * NV + 255) / 256, 256, 0, stream>>>(dcn_w, c2w, c3w, gamma, var, W1g, W2g, W3g);
    prep_bias<<<1, 256, 0, stream>>>(dcn_b, c2b, c3b, gamma, beta, mean, var, biasg);

    for (int i = 0; i < 8; i++) {
        int k = i & 3;
        int odd = i & 1;
        int H1 = odd ? 104 : 96;   // conv1 output grid (halo for odd branches)
        int H2 = odd ? 100 : 96;   // conv2 output grid

        dim3 g1((H1 + 15) / 16, (H1 + 7) / 8, B);
        conv_k<1, 0><<<g1, 256, 0, stream>>>(x, buf1, W1g + i * NV, biasg,
                                             96, 96, H1, H1, odd ? -4 : 0, 0);
        dim3 g2((H2 + 15) / 16, (H2 + 7) / 8, B);
        conv_k<2, 0><<<g2, 256, 0, stream>>>(buf1, buf2, W2g + k * NV, biasg + 64,
                                             H1, H1, H2, H2, odd ? 2 : 0, 0);
        dim3 g3(6, 12, B);
        conv_k<2, 1><<<g3, 256, 0, stream>>>(buf2, maxbuf, W3g + k * NV, biasg + 128,
                                             H2, H2, 96, 96, odd ? 2 : 0, (i == 0) ? 1 : 0);
    }
    final_k<<<(B * HW * HW + 255) / 256, 256, 0, stream>>>(maxbuf, (float*)d_out);
}

// Round 2
// 588.009 us; speedup vs baseline: 4.4242x; 4.4242x over previous
//
#include <hip/hip_runtime.h>
#include <math.h>

#define B 8
#define C 64
#define HW 96
#define NWV 36864            // per-variant weight elems: 9 taps * 64 co * 64 ci

typedef __attribute__((ext_vector_type(8))) short short8;
typedef __attribute__((ext_vector_type(4))) float floatx4;

__device__ __forceinline__ unsigned short f2bf(float f) {
    unsigned int u = __float_as_uint(f);
    unsigned int r = (u + 0x7fffu + ((u >> 16) & 1u)) >> 16;
    return (unsigned short)r;
}

// tap rotation: effective kernel for rotation k is K'[i,j] = r^k(K)[i,j], r(K)[i,j]=K[2-j,i]
__device__ __forceinline__ void rotmap(int k, int ta, int tb, int& sa, int& sb) {
    switch (k) {
        case 0: sa = ta;     sb = tb;     break;
        case 1: sa = 2 - tb; sb = ta;     break;
        case 2: sa = 2 - ta; sb = 2 - tb; break;
        default: sa = tb;    sb = 2 - ta; break;
    }
}

// ---------------- prep kernels ----------------

// Wall[variant][tap][co][ci]  bf16, BN-fused. variants: 0..7 conv1 branch i (roll folded),
// 8..11 conv2 rot k, 12..15 conv3 rot k.
__global__ void prep_w(const float* __restrict__ dcn_w, const float* __restrict__ c2w,
                       const float* __restrict__ c3w,
                       const float* __restrict__ gamma, const float* __restrict__ var_,
                       unsigned short* __restrict__ Wall) {
    int idx = blockIdx.x * 256 + threadIdx.x;
    if (idx >= 16 * NWV) return;
    int v = idx / NWV, rem = idx % NWV;
    int tap = rem >> 12;
    int co  = (rem >> 6) & 63;
    int ci  = rem & 63;
    int ta = tap / 3, tb = tap % 3;
    const float* src; int k, srcci, l;
    if (v < 8)       { k = v & 3;  srcci = (ci + 8 * v) & 63; src = dcn_w; l = 0; }
    else if (v < 12) { k = v - 8;  srcci = ci; src = c2w; l = 1; }
    else             { k = v - 12; srcci = ci; src = c3w; l = 2; }
    int sa, sb; rotmap(k, ta, tb, sa, sb);
    float s = gamma[l * 64 + co] * rsqrtf(var_[l * 64 + co] + 1e-5f);
    Wall[idx] = f2bf(src[((co * 64 + srcci) * 3 + sa) * 3 + sb] * s);
}

__global__ void prep_bias(const float* __restrict__ dcn_b, const float* __restrict__ c2b,
                          const float* __restrict__ c3b,
                          const float* __restrict__ gamma, const float* __restrict__ beta,
                          const float* __restrict__ mean, const float* __restrict__ var_,
                          float* __restrict__ biasg) {
    int t = threadIdx.x;
    if (t < 192) {
        int l = t >> 6, c = t & 63;
        const float* cb = (l == 0) ? dcn_b : ((l == 1) ? c2b : c3b);
        float s = gamma[l * 64 + c] * rsqrtf(var_[l * 64 + c] + 1e-5f);
        biasg[t] = cb[c] * s + beta[l * 64 + c] - mean[l * 64 + c] * s;
    }
}

// NCHW fp32 -> NHWC bf16. One block per (b, y): transpose 64c x 96x via LDS.
__global__ __launch_bounds__(256) void prep_x(const float* __restrict__ in,
                                              unsigned short* __restrict__ out) {
    __shared__ float row[64 * 97];
    int by = blockIdx.x;
    int b = by / 96, y = by % 96;
    int t = threadIdx.x;
    for (int e = t; e < 6144; e += 256) {
        int c = e / 96, x = e - c * 96;
        row[c * 97 + x] = in[(((size_t)(b * 64 + c) * 96 + y) * 96) + x];
    }
    __syncthreads();
    for (int e = t; e < 6144; e += 256) {
        int x = e >> 6, c = e & 63;
        out[(((size_t)(b * 96 + y) * 96 + x) << 6) + c] = f2bf(row[c * 97 + x]);
    }
}

// ---------------- MFMA conv: 3x3 dil-DIL, 64->64ch, bias+relu ----------------
// Block: 256 threads (4 waves). Tile: 64 co x (8 rows x 16 cols) pixels.
// Wave w: co in [16w,16w+16). A (weights) held in registers for full K=576.
// MODE 0: write relu(conv+bias) to NHWC bf16. MODE 1: max over 64 co -> maxbuf fp32.
template<int DIL, int MODE>
__global__ __launch_bounds__(256) void conv_mfma(
    const unsigned short* __restrict__ in, unsigned short* __restrict__ outb,
    float* __restrict__ outf,
    const unsigned short* __restrict__ Wg, const float* __restrict__ bias,
    int Hin, int Hout, int shift, int first) {

    constexpr int ROWS = 8 + 2 * DIL;
    constexpr int WT   = 16 + 2 * DIL;
    constexpr int NPIX = ROWS * WT;

    __shared__ __align__(16) unsigned short xt[NPIX * 64];
    __shared__ float red[512];

    int t    = threadIdx.x;
    int b    = blockIdx.z;
    int oy0  = blockIdx.y * 8;
    int ox0  = blockIdx.x * 16;
    int n    = t & 15;            // pixel-x within tile (B-frag col / D col)
    int q    = (t >> 4) & 3;      // k-group within wave
    int wave = t >> 6;
    int cobase = wave << 4;

    const unsigned short* inb = in + ((size_t)b * Hin * Hin << 6);

    // ---- load A fragments: A[m=lane&15 -> co][k = q*8+j -> ci], tap-major ----
    short8 A[18];
#pragma unroll
    for (int tap = 0; tap < 9; tap++)
#pragma unroll
        for (int half = 0; half < 2; half++)
            A[tap * 2 + half] = *(const short8*)(Wg + (tap * 4096 + (cobase + n) * 64
                                                       + half * 32 + q * 8));

    // ---- stage input tile (zero-padded OOB), xor-swizzled ci-groups ----
    for (int e = t; e < NPIX * 8; e += 256) {
        int p  = e >> 3, g = e & 7;
        int yy = p / WT, xx = p - yy * WT;
        int gy = oy0 + shift - DIL + yy;
        int gx = ox0 + shift - DIL + xx;
        uint4 v = make_uint4(0u, 0u, 0u, 0u);
        if ((unsigned)gy < (unsigned)Hin && (unsigned)gx < (unsigned)Hin)
            v = *(const uint4*)(inb + (((size_t)(gy * Hin + gx)) << 6) + (g << 3));
        *(uint4*)(&xt[(p << 6) + ((g ^ (xx & 7)) << 3)]) = v;
    }
    __syncthreads();

    // ---- K loop: 9 taps x 2 ci-halves, 8 row-subtiles each ----
    floatx4 acc[8];
#pragma unroll
    for (int r = 0; r < 8; r++) acc[r] = (floatx4){0.f, 0.f, 0.f, 0.f};

#pragma unroll
    for (int tap = 0; tap < 9; tap++) {
        int ta = tap / 3, tb = tap % 3;
        int xx = n + tb * DIL;
        int key = xx & 7;
#pragma unroll
        for (int half = 0; half < 2; half++) {
            short8 a = A[tap * 2 + half];
            int g = half * 4 + q;
            int cioff = ((g ^ key) << 3);
#pragma unroll
            for (int r = 0; r < 8; r++) {
                int p = (r + ta * DIL) * WT + xx;
                short8 bf = *(const short8*)(&xt[(p << 6) + cioff]);
                acc[r] = __builtin_amdgcn_mfma_f32_16x16x32_bf16(a, bf, acc[r], 0, 0, 0);
            }
        }
    }

    // ---- epilogue ----
    float bv[4];
#pragma unroll
    for (int reg = 0; reg < 4; reg++) bv[reg] = bias[cobase + q * 4 + reg];

    if (MODE == 0) {
        unsigned short* ob = outb + ((size_t)b * Hout * Hout << 6);
#pragma unroll
        for (int r = 0; r < 8; r++) {
            int oy = oy0 + r, ox = ox0 + n;
            if (oy < Hout && ox < Hout) {
#pragma unroll
                for (int reg = 0; reg < 4; reg++) {
                    int co = cobase + q * 4 + reg;
                    float vv = fmaxf(acc[r][reg] + bv[reg], 0.f);
                    ob[(((size_t)(oy * Hout + ox)) << 6) + co] = f2bf(vv);
                }
            }
        }
    } else {
        // max over this wave's 4 co (regs) then across k-groups (lanes +16,+32)
#pragma unroll
        for (int r = 0; r < 8; r++) {
            float m = 0.f;
#pragma unroll
            for (int reg = 0; reg < 4; reg++) m = fmaxf(m, acc[r][reg] + bv[reg]);
            m = fmaxf(m, __shfl_xor(m, 16, 64));
            m = fmaxf(m, __shfl_xor(m, 32, 64));
            if ((t & 63) < 16) red[wave * 128 + r * 16 + n] = m;
        }
        __syncthreads();
        if (t < 128) {
            float m = red[t];
#pragma unroll
            for (int w = 1; w < 4; w++) m = fmaxf(m, red[w * 128 + t]);
            m = fmaxf(m, 0.f);  // relu
            int oy = oy0 + (t >> 4), ox = ox0 + (t & 15);
            size_t o = (size_t)b * 9216 + oy * 96 + ox;
            outf[o] = first ? m : fmaxf(outf[o], m);
        }
    }
}

__global__ void final_k(const float* __restrict__ maxbuf, float* __restrict__ out) {
    int i = blockIdx.x * 256 + threadIdx.x;
    if (i < B * HW * HW) {
        float v = 1.f / (1.f + expf(-maxbuf[i]));
        out[i] = fminf(fmaxf(v, 1e-4f), 1.f - 1e-4f);
    }
}

// ---------------- launch ----------------

extern "C" void kernel_launch(void* const* d_in, const int* in_sizes, int n_in,
                              void* d_out, int out_size, void* d_ws, size_t ws_size,
                              hipStream_t stream) {
    const float* x     = (const float*)d_in[0];
    const float* dcn_w = (const float*)d_in[2];
    const float* dcn_b = (const float*)d_in[3];
    const float* c2w   = (const float*)d_in[4];
    const float* c2b   = (const float*)d_in[5];
    const float* c3w   = (const float*)d_in[6];
    const float* c3b   = (const float*)d_in[7];
    const float* gamma = (const float*)d_in[8];
    const float* beta  = (const float*)d_in[9];
    const float* mean  = (const float*)d_in[10];
    const float* var_  = (const float*)d_in[11];

    char* ws = (char*)d_ws;
    unsigned short* Wall = (unsigned short*)ws;                 // 16*NWV bf16 = 1.18MB
    size_t off = (size_t)16 * NWV * 2;
    float* biasg = (float*)(ws + off);           off += 1024;   // 192 f32
    float* maxbuf = (float*)(ws + off);          off += (size_t)B * HW * HW * 4;
    unsigned short* xhwc = (unsigned short*)(ws + off); off += (size_t)B * 96 * 96 * 64 * 2;
    unsigned short* buf1 = (unsigned short*)(ws + off); off += (size_t)B * 104 * 104 * 64 * 2;
    unsigned short* buf2 = (unsigned short*)(ws + off);

    prep_w<<<(16 * NWV + 255) / 256, 256, 0, stream>>>(dcn_w, c2w, c3w, gamma, var_, Wall);
    prep_bias<<<1, 256, 0, stream>>>(dcn_b, c2b, c3b, gamma, beta, mean, var_, biasg);
    prep_x<<<B * 96, 256, 0, stream>>>(x, xhwc);

    for (int i = 0; i < 8; i++) {
        int k = i & 3;
        int odd = i & 1;
        int H1 = odd ? 104 : 96;
        int H2 = odd ? 100 : 96;

        dim3 g1((H1 + 15) / 16, (H1 + 7) / 8, B);
        conv_mfma<1, 0><<<g1, 256, 0, stream>>>(
            xhwc, buf1, nullptr, Wall + (size_t)i * NWV, biasg,
            96, H1, odd ? -4 : 0, 0);

        dim3 g2((H2 + 15) / 16, (H2 + 7) / 8, B);
        conv_mfma<2, 0><<<g2, 256, 0, stream>>>(
            buf1, buf2, nullptr, Wall + (size_t)(8 + k) * NWV, biasg + 64,
            H1, H2, odd ? 2 : 0, 0);

        dim3 g3(6, 12, B);
        conv_mfma<2, 1><<<g3, 256, 0, stream>>>(
            buf2, nullptr, maxbuf, Wall + (size_t)(12 + k) * NWV, biasg + 128,
            H2, 96, odd ? 2 : 0, (i == 0) ? 1 : 0);
    }
    final_k<<<(B * HW * HW + 255) / 256, 256, 0, stream>>>(maxbuf, (float*)d_out);
}

// Round 3
// 379.955 us; speedup vs baseline: 6.8469x; 1.5476x over previous
//
#include <hip/hip_runtime.h>
#include <math.h>

#define B 8
#define C 64
#define HW 96
#define NWV 36864            // per-variant weight elems: 9 taps * 64 co * 64 ci

typedef __attribute__((ext_vector_type(8)))  short short8;
typedef __attribute__((ext_vector_type(16))) float floatx16;

__device__ __forceinline__ unsigned short f2bf(float f) {
    unsigned int u = __float_as_uint(f);
    unsigned int r = (u + 0x7fffu + ((u >> 16) & 1u)) >> 16;
    return (unsigned short)r;
}

// tap rotation: effective kernel for rotation k is K'[i,j] = r^k(K)[i,j], r(K)[i,j]=K[2-j,i]
__device__ __forceinline__ void rotmap(int k, int ta, int tb, int& sa, int& sb) {
    switch (k) {
        case 0: sa = ta;     sb = tb;     break;
        case 1: sa = 2 - tb; sb = ta;     break;
        case 2: sa = 2 - ta; sb = 2 - tb; break;
        default: sa = tb;    sb = 2 - ta; break;
    }
}

// ---------------- prep kernels ----------------

// Frag-contiguous weight layout per variant:
//   idx = (((tap*4 + ks)*2 + cof)*64 + lane)*8 + j
//   co = cof*32 + (lane&31); ci = ks*16 + (lane>>5)*8 + j
// variants: 0..7 conv1 branch i (channel roll folded), 8..11 conv2 rot k, 12..15 conv3 rot k.
__global__ void prep_w(const float* __restrict__ dcn_w, const float* __restrict__ c2w,
                       const float* __restrict__ c3w,
                       const float* __restrict__ gamma, const float* __restrict__ var_,
                       unsigned short* __restrict__ Wall) {
    int idx = blockIdx.x * 256 + threadIdx.x;
    if (idx >= 16 * NWV) return;
    int v = idx / NWV, rem = idx % NWV;
    int tap  = rem >> 12;
    int w12  = rem & 4095;
    int ks   = w12 >> 10;
    int cof  = (w12 >> 9) & 1;
    int lane = (w12 >> 3) & 63;
    int j    = w12 & 7;
    int co = cof * 32 + (lane & 31);
    int ci = ks * 16 + (lane >> 5) * 8 + j;
    int ta = tap / 3, tb = tap % 3;
    const float* src; int k, srcci, l;
    if (v < 8)       { k = v & 3;  srcci = (ci + 8 * v) & 63; src = dcn_w; l = 0; }
    else if (v < 12) { k = v - 8;  srcci = ci; src = c2w; l = 1; }
    else             { k = v - 12; srcci = ci; src = c3w; l = 2; }
    int sa, sb; rotmap(k, ta, tb, sa, sb);
    float s = gamma[l * 64 + co] * rsqrtf(var_[l * 64 + co] + 1e-5f);
    Wall[idx] = f2bf(src[((co * 64 + srcci) * 3 + sa) * 3 + sb] * s);
}

__global__ void prep_bias(const float* __restrict__ dcn_b, const float* __restrict__ c2b,
                          const float* __restrict__ c3b,
                          const float* __restrict__ gamma, const float* __restrict__ beta,
                          const float* __restrict__ mean, const float* __restrict__ var_,
                          float* __restrict__ biasg) {
    int t = threadIdx.x;
    if (t < 192) {
        int l = t >> 6, c = t & 63;
        const float* cb = (l == 0) ? dcn_b : ((l == 1) ? c2b : c3b);
        float s = gamma[l * 64 + c] * rsqrtf(var_[l * 64 + c] + 1e-5f);
        biasg[t] = cb[c] * s + beta[l * 64 + c] - mean[l * 64 + c] * s;
    }
}

// NCHW fp32 -> NHWC bf16.
__global__ __launch_bounds__(256) void prep_x(const float* __restrict__ in,
                                              unsigned short* __restrict__ out) {
    __shared__ float row[64 * 97];
    int by = blockIdx.x;
    int b = by / 96, y = by % 96;
    int t = threadIdx.x;
    for (int e = t; e < 6144; e += 256) {
        int c = e / 96, x = e - c * 96;
        row[c * 97 + x] = in[(((size_t)(b * 64 + c) * 96 + y) * 96) + x];
    }
    __syncthreads();
    for (int e = t; e < 6144; e += 256) {
        int x = e >> 6, c = e & 63;
        out[(((size_t)(b * 96 + y) * 96 + x) << 6) + c] = f2bf(row[c * 97 + x]);
    }
}

// ---------------- fused MFMA conv layer (all 8 branches in one dispatch) ----------------
// Block: 256 threads (4 waves). Tile: 64 co x 8 rows x 32 cols.
// Wave w: rows {2w, 2w+1}; all 64 co (2 A-frags); 32x32x16 MFMA, 2 MFMAs per B ds_read.
// A-frags loaded from global (frag-contiguous, L1-hot). Input tile staged once, full K.
// LAYER 0: dil1, in xhwc(96) -> buf1; LAYER 1: dil2 buf1->buf2; LAYER 2: dil2 buf2->maxb.
template<int LAYER>
__global__ __launch_bounds__(256) void conv32(
    const unsigned short* __restrict__ in, unsigned short* __restrict__ outb,
    float* __restrict__ maxb,
    const unsigned short* __restrict__ Wall, const float* __restrict__ biasg) {

    constexpr int DIL = (LAYER == 0) ? 1 : 2;
    constexpr int WT  = 32 + 2 * DIL;
    constexpr int RT  = 8 + 2 * DIL;

    __shared__ __align__(16) unsigned short xt[RT * WT * 64];
    __shared__ float bs[64];

    int z  = blockIdx.z;
    int br = z >> 3;           // branch 0..7
    int b  = z & 7;            // image
    int odd = br & 1;

    int Hin, Hout, shift;
    if (LAYER == 0)      { Hin = 96;             Hout = odd ? 104 : 96; shift = odd ? -4 : 0; }
    else if (LAYER == 1) { Hin = odd ? 104 : 96; Hout = odd ? 100 : 96; shift = odd ?  2 : 0; }
    else                 { Hin = odd ? 100 : 96; Hout = 96;             shift = odd ?  2 : 0; }

    int oy0 = blockIdx.y * 8;
    int ox0 = blockIdx.x * 32;
    if (oy0 >= Hout || ox0 >= Hout) return;   // uniform per block

    int variant = (LAYER == 0) ? br : ((LAYER == 1) ? 8 + (br & 3) : 12 + (br & 3));
    const short8* Ag = (const short8*)(Wall + (size_t)variant * NWV);

    size_t in_stride = (LAYER == 0) ? (size_t)96 * 96 * 64
                     : (LAYER == 1) ? (size_t)104 * 104 * 64
                                    : (size_t)100 * 100 * 64;
    const unsigned short* inb = in + ((LAYER == 0) ? (size_t)b : (size_t)z) * in_stride;

    int t = threadIdx.x;
    if (t < 64) bs[t] = biasg[LAYER * 64 + t];

    // ---- stage input tile (zero-padded OOB), xor-swizzled 16B ci-groups ----
    for (int e = t; e < RT * WT * 8; e += 256) {
        int p = e >> 3, g = e & 7;
        int yy = p / WT, xx = p - yy * WT;
        int gy = oy0 + shift - DIL + yy;
        int gx = ox0 + shift - DIL + xx;
        uint4 v = make_uint4(0u, 0u, 0u, 0u);
        if ((unsigned)gy < (unsigned)Hin && (unsigned)gx < (unsigned)Hin)
            v = *(const uint4*)(inb + (((size_t)(gy * Hin + gx)) << 6) + (g << 3));
        *(uint4*)(&xt[(p << 6) + ((g ^ (xx & 7)) << 3)]) = v;
    }
    __syncthreads();

    int lane = t & 63, wv = t >> 6;
    int n  = lane & 31;        // pixel col within 32  (B-frag n / D col)
    int kq = lane >> 5;        // k-half within 16-step

    floatx16 acc[2][2];        // [cof][pf]
#pragma unroll
    for (int cf = 0; cf < 2; cf++)
#pragma unroll
        for (int pf = 0; pf < 2; pf++)
#pragma unroll
            for (int i = 0; i < 16; i++) acc[cf][pf][i] = 0.f;

#pragma unroll 3
    for (int tap = 0; tap < 9; tap++) {
        int ta = tap / 3, tb = tap - ta * 3;
        short8 a[4][2];
#pragma unroll
        for (int ks = 0; ks < 4; ks++)
#pragma unroll
            for (int cf = 0; cf < 2; cf++)
                a[ks][cf] = Ag[((tap * 4 + ks) * 2 + cf) * 64 + lane];

        int xb  = n + tb * DIL;
        int key = xb & 7;
#pragma unroll
        for (int ks = 0; ks < 4; ks++) {
            int cig = (((ks * 2 + kq) ^ key) << 3);
#pragma unroll
            for (int pf = 0; pf < 2; pf++) {
                int row = wv * 2 + pf + ta * DIL;
                short8 bfr = *(const short8*)(&xt[((row * WT + xb) << 6) + cig]);
                acc[0][pf] = __builtin_amdgcn_mfma_f32_32x32x16_bf16(a[ks][0], bfr, acc[0][pf], 0, 0, 0);
                acc[1][pf] = __builtin_amdgcn_mfma_f32_32x32x16_bf16(a[ks][1], bfr, acc[1][pf], 0, 0, 0);
            }
        }
    }

    // ---- epilogue ----
    // D layout: col = lane&31 = pixel n; row(co) = (reg&3) + 8*(reg>>2) + 4*kq (+32*cof)
    if (LAYER < 2) {
        unsigned short* ob = outb + (size_t)z * ((LAYER == 0) ? (size_t)104 * 104 * 64
                                                              : (size_t)100 * 100 * 64);
#pragma unroll
        for (int pf = 0; pf < 2; pf++) {
            int oy = oy0 + wv * 2 + pf;
            int ox = ox0 + n;
            if (oy < Hout && ox < Hout) {
                size_t pbase = ((size_t)(oy * Hout + ox)) << 6;
#pragma unroll
                for (int cf = 0; cf < 2; cf++)
#pragma unroll
                    for (int rb = 0; rb < 4; rb++) {
                        int co0 = cf * 32 + 4 * kq + 8 * rb;
                        unsigned int lo, hi;
                        float v0 = fmaxf(acc[cf][pf][rb * 4 + 0] + bs[co0 + 0], 0.f);
                        float v1 = fmaxf(acc[cf][pf][rb * 4 + 1] + bs[co0 + 1], 0.f);
                        float v2 = fmaxf(acc[cf][pf][rb * 4 + 2] + bs[co0 + 2], 0.f);
                        float v3 = fmaxf(acc[cf][pf][rb * 4 + 3] + bs[co0 + 3], 0.f);
                        lo = (unsigned int)f2bf(v0) | ((unsigned int)f2bf(v1) << 16);
                        hi = (unsigned int)f2bf(v2) | ((unsigned int)f2bf(v3) << 16);
                        *(uint2*)(ob + pbase + co0) = make_uint2(lo, hi);
                    }
            }
        }
    } else {
#pragma unroll
        for (int pf = 0; pf < 2; pf++) {
            float mx = 0.f;
#pragma unroll
            for (int cf = 0; cf < 2; cf++)
#pragma unroll
                for (int rb = 0; rb < 4; rb++)
#pragma unroll
                    for (int i = 0; i < 4; i++) {
                        int co = cf * 32 + 4 * kq + 8 * rb + i;
                        mx = fmaxf(mx, acc[cf][pf][rb * 4 + i] + bs[co]);
                    }
            mx = fmaxf(mx, __shfl_xor(mx, 32, 64));
            if (lane < 32) {
                int oy = oy0 + wv * 2 + pf;
                maxb[((size_t)z * 96 + oy) * 96 + ox0 + n] = mx;
            }
        }
    }
}

__global__ void final_k(const float* __restrict__ maxb, float* __restrict__ out) {
    int i = blockIdx.x * 256 + threadIdx.x;
    if (i < B * HW * HW) {
        int b = i / 9216, yx = i - b * 9216;
        float m = 0.f;
#pragma unroll
        for (int br = 0; br < 8; br++)
            m = fmaxf(m, maxb[((size_t)(br * 8 + b)) * 9216 + yx]);
        float v = 1.f / (1.f + expf(-m));
        out[i] = fminf(fmaxf(v, 1e-4f), 1.f - 1e-4f);
    }
}

// ---------------- launch ----------------

extern "C" void kernel_launch(void* const* d_in, const int* in_sizes, int n_in,
                              void* d_out, int out_size, void* d_ws, size_t ws_size,
                              hipStream_t stream) {
    const float* x     = (const float*)d_in[0];
    const float* dcn_w = (const float*)d_in[2];
    const float* dcn_b = (const float*)d_in[3];
    const float* c2w   = (const float*)d_in[4];
    const float* c2b   = (const float*)d_in[5];
    const float* c3w   = (const float*)d_in[6];
    const float* c3b   = (const float*)d_in[7];
    const float* gamma = (const float*)d_in[8];
    const float* beta  = (const float*)d_in[9];
    const float* mean  = (const float*)d_in[10];
    const float* var_  = (const float*)d_in[11];

    char* ws = (char*)d_ws;
    unsigned short* Wall = (unsigned short*)ws;                       // 1.18 MB
    size_t off = (size_t)16 * NWV * 2;
    float* biasg = (float*)(ws + off);            off += 1024;
    float* maxb  = (float*)(ws + off);            off += (size_t)64 * 9216 * 4;       // 2.36 MB
    unsigned short* xhwc = (unsigned short*)(ws + off); off += (size_t)B * 9216 * 64 * 2;   // 9.4 MB
    unsigned short* buf1 = (unsigned short*)(ws + off); off += (size_t)64 * 104 * 104 * 64 * 2; // 88.6 MB
    unsigned short* buf2 = (unsigned short*)(ws + off);                                // 81.9 MB

    prep_w<<<(16 * NWV + 255) / 256, 256, 0, stream>>>(dcn_w, c2w, c3w, gamma, var_, Wall);
    prep_bias<<<1, 256, 0, stream>>>(dcn_b, c2b, c3b, gamma, beta, mean, var_, biasg);
    prep_x<<<B * 96, 256, 0, stream>>>(x, xhwc);

    dim3 g12(4, 13, 64);
    conv32<0><<<g12, 256, 0, stream>>>(xhwc, buf1, nullptr, Wall, biasg);
    conv32<1><<<g12, 256, 0, stream>>>(buf1, buf2, nullptr, Wall, biasg);
    dim3 g3(3, 12, 64);
    conv32<2><<<g3, 256, 0, stream>>>(buf2, nullptr, maxb, Wall, biasg);

    final_k<<<(B * HW * HW + 255) / 256, 256, 0, stream>>>(maxb, (float*)d_out);
}

// Round 4
// 351.829 us; speedup vs baseline: 7.3942x; 1.0799x over previous
//
#include <hip/hip_runtime.h>
#include <math.h>

#define B 8
#define C 64
#define HW 96
#define NWV 36864            // per-variant weight elems: 9 taps * 64 co * 64 ci

typedef __attribute__((ext_vector_type(8)))  short short8;
typedef __attribute__((ext_vector_type(16))) float floatx16;

__device__ __forceinline__ unsigned short f2bf(float f) {
    unsigned int u = __float_as_uint(f);
    unsigned int r = (u + 0x7fffu + ((u >> 16) & 1u)) >> 16;
    return (unsigned short)r;
}

// tap rotation: effective kernel for rotation k is K'[i,j] = r^k(K)[i,j], r(K)[i,j]=K[2-j,i]
__device__ __forceinline__ void rotmap(int k, int ta, int tb, int& sa, int& sb) {
    switch (k) {
        case 0: sa = ta;     sb = tb;     break;
        case 1: sa = 2 - tb; sb = ta;     break;
        case 2: sa = 2 - ta; sb = 2 - tb; break;
        default: sa = tb;    sb = 2 - ta; break;
    }
}

// ---------------- prep kernels ----------------

// Frag-contiguous weight layout per variant:
//   idx = (((tap*4 + ks)*2 + cf)*64 + lane)*8 + j
//   co = cf*32 + (lane&31); ci = ks*16 + (lane>>5)*8 + j
__global__ void prep_w(const float* __restrict__ dcn_w, const float* __restrict__ c2w,
                       const float* __restrict__ c3w,
                       const float* __restrict__ gamma, const float* __restrict__ var_,
                       unsigned short* __restrict__ Wall) {
    int idx = blockIdx.x * 256 + threadIdx.x;
    if (idx >= 16 * NWV) return;
    int v = idx / NWV, rem = idx % NWV;
    int tap  = rem >> 12;
    int w12  = rem & 4095;
    int ks   = w12 >> 10;
    int cf   = (w12 >> 9) & 1;
    int lane = (w12 >> 3) & 63;
    int j    = w12 & 7;
    int co = cf * 32 + (lane & 31);
    int ci = ks * 16 + (lane >> 5) * 8 + j;
    int ta = tap / 3, tb = tap % 3;
    const float* src; int k, srcci, l;
    if (v < 8)       { k = v & 3;  srcci = (ci + 8 * v) & 63; src = dcn_w; l = 0; }
    else if (v < 12) { k = v - 8;  srcci = ci; src = c2w; l = 1; }
    else             { k = v - 12; srcci = ci; src = c3w; l = 2; }
    int sa, sb; rotmap(k, ta, tb, sa, sb);
    float s = gamma[l * 64 + co] * rsqrtf(var_[l * 64 + co] + 1e-5f);
    Wall[idx] = f2bf(src[((co * 64 + srcci) * 3 + sa) * 3 + sb] * s);
}

__global__ void prep_bias(const float* __restrict__ dcn_b, const float* __restrict__ c2b,
                          const float* __restrict__ c3b,
                          const float* __restrict__ gamma, const float* __restrict__ beta,
                          const float* __restrict__ mean, const float* __restrict__ var_,
                          float* __restrict__ biasg) {
    int t = threadIdx.x;
    if (t < 192) {
        int l = t >> 6, c = t & 63;
        const float* cb = (l == 0) ? dcn_b : ((l == 1) ? c2b : c3b);
        float s = gamma[l * 64 + c] * rsqrtf(var_[l * 64 + c] + 1e-5f);
        biasg[t] = cb[c] * s + beta[l * 64 + c] - mean[l * 64 + c] * s;
    }
}

// NCHW fp32 -> NHWC bf16.
__global__ __launch_bounds__(256) void prep_x(const float* __restrict__ in,
                                              unsigned short* __restrict__ out) {
    __shared__ float row[64 * 97];
    int by = blockIdx.x;
    int b = by / 96, y = by % 96;
    int t = threadIdx.x;
    for (int e = t; e < 6144; e += 256) {
        int c = e / 96, x = e - c * 96;
        row[c * 97 + x] = in[(((size_t)(b * 64 + c) * 96 + y) * 96) + x];
    }
    __syncthreads();
    for (int e = t; e < 6144; e += 256) {
        int x = e >> 6, c = e & 63;
        out[(((size_t)(b * 96 + y) * 96 + x) << 6) + c] = f2bf(row[c * 97 + x]);
    }
}

// ---------------- fused MFMA conv layer (all 8 branches, one dispatch) ----------------
// Block: 256 threads (4 waves). Tile: 64 co x 16 rows x 32 cols (512 px).
// Wave w: rows 4w..4w+3 (4 row-frags), all 64 co (2 co-frags). 32x32x16 MFMA.
// ci split in 2 stages of 32 (LDS ~46KB -> 2 blocks/CU). B-frags register-cached
// across (ta,pf): each ds_read_b128 feeds 3 MFMAs. A from global (L1/L2-hot).
template<int LAYER>
__global__ __launch_bounds__(256, 2) void conv_t(
    const unsigned short* __restrict__ in, unsigned short* __restrict__ outb,
    float* __restrict__ maxb,
    const unsigned short* __restrict__ Wall, const float* __restrict__ biasg) {

    constexpr int DIL = (LAYER == 0) ? 1 : 2;
    constexpr int WT  = 32 + 2 * DIL;
    constexpr int RT  = 16 + 2 * DIL;
    constexpr int NR  = 4 + 2 * DIL;     // distinct B-row-frags per (tb,ks) per wave

    __shared__ __align__(16) unsigned short xt[RT * WT * 32];
    __shared__ float bs[64];

    int z  = blockIdx.z;
    int br = z >> 3;
    int b  = z & 7;
    int odd = br & 1;

    int Hin, Hout, shift;
    if (LAYER == 0)      { Hin = 96;             Hout = odd ? 104 : 96; shift = odd ? -4 : 0; }
    else if (LAYER == 1) { Hin = odd ? 104 : 96; Hout = odd ? 100 : 96; shift = odd ?  2 : 0; }
    else                 { Hin = odd ? 100 : 96; Hout = 96;             shift = odd ?  2 : 0; }

    int oy0 = blockIdx.y * 16;
    int ox0 = blockIdx.x * 32;
    if (oy0 >= Hout || ox0 >= Hout) return;

    int variant = (LAYER == 0) ? br : ((LAYER == 1) ? 8 + (br & 3) : 12 + (br & 3));
    const short8* Ag = (const short8*)(Wall + (size_t)variant * NWV);

    size_t in_stride = (LAYER == 0) ? (size_t)96 * 96 * 64
                     : (LAYER == 1) ? (size_t)104 * 104 * 64
                                    : (size_t)100 * 100 * 64;
    const unsigned short* inb = in + ((LAYER == 0) ? (size_t)b : (size_t)z) * in_stride;

    int t = threadIdx.x;
    if (t < 64) bs[t] = biasg[LAYER * 64 + t];

    int lane = t & 63, wv = t >> 6;
    int n  = lane & 31;           // pixel col (B-frag n / D col)
    int kq = lane >> 5;           // k-half within K=16
    int rowbase = wv << 2;        // wave's first tile row

    floatx16 acc[2][4];
#pragma unroll
    for (int cf = 0; cf < 2; cf++)
#pragma unroll
        for (int pf = 0; pf < 4; pf++)
#pragma unroll
            for (int i = 0; i < 16; i++) acc[cf][pf][i] = 0.f;

    for (int s = 0; s < 2; s++) {
        if (s) __syncthreads();
        // ---- stage 32 ci (4 chunks of 8), xor-swizzled ----
        for (int e = t; e < RT * WT * 4; e += 256) {
            int p = e >> 2, g = e & 3;
            int yy = p / WT, xx = p - yy * WT;
            int gy = oy0 + shift - DIL + yy;
            int gx = ox0 + shift - DIL + xx;
            uint4 v = make_uint4(0u, 0u, 0u, 0u);
            if ((unsigned)gy < (unsigned)Hin && (unsigned)gx < (unsigned)Hin)
                v = *(const uint4*)(inb + (((size_t)(gy * Hin + gx)) << 6) + (s << 5) + (g << 3));
            *(uint4*)(&xt[(p << 5) + ((g ^ (xx & 3)) << 3)]) = v;
        }
        __syncthreads();

#pragma unroll
        for (int tb = 0; tb < 3; tb++) {
#pragma unroll
            for (int kl = 0; kl < 2; kl++) {
                int ksg = s * 2 + kl;
                // A-frags for the 3 vertical taps x 2 co-frags of this (tb,ks)
                short8 a[3][2];
#pragma unroll
                for (int ta = 0; ta < 3; ta++)
#pragma unroll
                    for (int cf = 0; cf < 2; cf++)
                        a[ta][cf] = Ag[(((ta * 3 + tb) * 4 + ksg) * 2 + cf) * 64 + lane];

                int xb = n + tb * DIL;
                int cidx = ((kl * 2 + kq) ^ (xb & 3)) << 3;
                // B row-frags rowbase+0..NR-1, each reused across (ta,pf) pairs
                short8 bf[NR];
#pragma unroll
                for (int rr = 0; rr < NR; rr++)
                    bf[rr] = *(const short8*)(&xt[((((rowbase + rr) * WT + xb)) << 5) + cidx]);
#pragma unroll
                for (int ta = 0; ta < 3; ta++)
#pragma unroll
                    for (int pf = 0; pf < 4; pf++) {
                        int rr = pf + ta * DIL;
                        acc[0][pf] = __builtin_amdgcn_mfma_f32_32x32x16_bf16(a[ta][0], bf[rr], acc[0][pf], 0, 0, 0);
                        acc[1][pf] = __builtin_amdgcn_mfma_f32_32x32x16_bf16(a[ta][1], bf[rr], acc[1][pf], 0, 0, 0);
                    }
            }
        }
    }

    // ---- epilogue ----
    // D layout (32x32): col = lane&31 = pixel n; row(co) = (reg&3) + 8*(reg>>2) + 4*kq + 32*cf
    if (LAYER < 2) {
        unsigned short* ob = outb + (size_t)z * ((LAYER == 0) ? (size_t)104 * 104 * 64
                                                              : (size_t)100 * 100 * 64);
        int ox = ox0 + n;
#pragma unroll
        for (int pf = 0; pf < 4; pf++) {
            int oy = oy0 + rowbase + pf;
            if (oy < Hout && ox < Hout) {
                size_t pbase = ((size_t)(oy * Hout + ox)) << 6;
#pragma unroll
                for (int cf = 0; cf < 2; cf++)
#pragma unroll
                    for (int rb = 0; rb < 4; rb++) {
                        int co0 = cf * 32 + 4 * kq + 8 * rb;
                        float v0 = fmaxf(acc[cf][pf][rb * 4 + 0] + bs[co0 + 0], 0.f);
                        float v1 = fmaxf(acc[cf][pf][rb * 4 + 1] + bs[co0 + 1], 0.f);
                        float v2 = fmaxf(acc[cf][pf][rb * 4 + 2] + bs[co0 + 2], 0.f);
                        float v3 = fmaxf(acc[cf][pf][rb * 4 + 3] + bs[co0 + 3], 0.f);
                        unsigned int lo = (unsigned int)f2bf(v0) | ((unsigned int)f2bf(v1) << 16);
                        unsigned int hi = (unsigned int)f2bf(v2) | ((unsigned int)f2bf(v3) << 16);
                        *(uint2*)(ob + pbase + co0) = make_uint2(lo, hi);
                    }
            }
        }
    } else {
#pragma unroll
        for (int pf = 0; pf < 4; pf++) {
            float mx = 0.f;
#pragma unroll
            for (int cf = 0; cf < 2; cf++)
#pragma unroll
                for (int rb = 0; rb < 4; rb++)
#pragma unroll
                    for (int i = 0; i < 4; i++) {
                        int co = cf * 32 + 4 * kq + 8 * rb + i;
                        mx = fmaxf(mx, acc[cf][pf][rb * 4 + i] + bs[co]);
                    }
            mx = fmaxf(mx, __shfl_xor(mx, 32, 64));
            if (lane < 32) {
                int oy = oy0 + rowbase + pf;
                maxb[((size_t)z * 96 + oy) * 96 + ox0 + n] = mx;
            }
        }
    }
}

__global__ void final_k(const float* __restrict__ maxb, float* __restrict__ out) {
    int i = blockIdx.x * 256 + threadIdx.x;
    if (i < B * HW * HW) {
        int b = i / 9216, yx = i - b * 9216;
        float m = 0.f;
#pragma unroll
        for (int br = 0; br < 8; br++)
            m = fmaxf(m, maxb[((size_t)(br * 8 + b)) * 9216 + yx]);
        float v = 1.f / (1.f + expf(-m));
        out[i] = fminf(fmaxf(v, 1e-4f), 1.f - 1e-4f);
    }
}

// ---------------- launch ----------------

extern "C" void kernel_launch(void* const* d_in, const int* in_sizes, int n_in,
                              void* d_out, int out_size, void* d_ws, size_t ws_size,
                              hipStream_t stream) {
    const float* x     = (const float*)d_in[0];
    const float* dcn_w = (const float*)d_in[2];
    const float* dcn_b = (const float*)d_in[3];
    const float* c2w   = (const float*)d_in[4];
    const float* c2b   = (const float*)d_in[5];
    const float* c3w   = (const float*)d_in[6];
    const float* c3b   = (const float*)d_in[7];
    const float* gamma = (const float*)d_in[8];
    const float* beta  = (const float*)d_in[9];
    const float* mean  = (const float*)d_in[10];
    const float* var_  = (const float*)d_in[11];

    char* ws = (char*)d_ws;
    unsigned short* Wall = (unsigned short*)ws;                       // 1.18 MB
    size_t off = (size_t)16 * NWV * 2;
    float* biasg = (float*)(ws + off);            off += 1024;
    float* maxb  = (float*)(ws + off);            off += (size_t)64 * 9216 * 4;
    unsigned short* xhwc = (unsigned short*)(ws + off); off += (size_t)B * 9216 * 64 * 2;
    unsigned short* buf1 = (unsigned short*)(ws + off); off += (size_t)64 * 104 * 104 * 64 * 2;
    unsigned short* buf2 = (unsigned short*)(ws + off);

    prep_w<<<(16 * NWV + 255) / 256, 256, 0, stream>>>(dcn_w, c2w, c3w, gamma, var_, Wall);
    prep_bias<<<1, 256, 0, stream>>>(dcn_b, c2b, c3b, gamma, beta, mean, var_, biasg);
    prep_x<<<B * 96, 256, 0, stream>>>(x, xhwc);

    dim3 g01(4, 7, 64);
    conv_t<0><<<g01, 256, 0, stream>>>(xhwc, buf1, nullptr, Wall, biasg);
    conv_t<1><<<g01, 256, 0, stream>>>(buf1, buf2, nullptr, Wall, biasg);
    dim3 g2(3, 6, 64);
    conv_t<2><<<g2, 256, 0, stream>>>(buf2, nullptr, maxb, Wall, biasg);

    final_k<<<(B * HW * HW + 255) / 256, 256, 0, stream>>>(maxb, (float*)d_out);
}

// Round 5
// 310.498 us; speedup vs baseline: 8.3785x; 1.1331x over previous
//
#include <hip/hip_runtime.h>
#include <math.h>

#define B 8
#define C 64
#define HW 96
#define NWV 36864            // per-variant weight elems: 9 taps * 64 co * 64 ci

typedef __attribute__((ext_vector_type(8)))  short short8;
typedef __attribute__((ext_vector_type(16))) float floatx16;

__device__ __forceinline__ unsigned short f2bf(float f) {
    unsigned int u = __float_as_uint(f);
    unsigned int r = (u + 0x7fffu + ((u >> 16) & 1u)) >> 16;
    return (unsigned short)r;
}

// tap rotation: effective kernel for rotation k is K'[i,j] = r^k(K)[i,j], r(K)[i,j]=K[2-j,i]
__device__ __forceinline__ void rotmap(int k, int ta, int tb, int& sa, int& sb) {
    switch (k) {
        case 0: sa = ta;     sb = tb;     break;
        case 1: sa = 2 - tb; sb = ta;     break;
        case 2: sa = 2 - ta; sb = 2 - tb; break;
        default: sa = tb;    sb = 2 - ta; break;
    }
}

// ---------------- prep kernels (unchanged from r4) ----------------
// Frag-contiguous weight layout per variant:
//   idx = (((tap*4 + ks)*2 + cf)*64 + lane)*8 + j
//   co = cf*32 + (lane&31); ci = ks*16 + (lane>>5)*8 + j
__global__ void prep_w(const float* __restrict__ dcn_w, const float* __restrict__ c2w,
                       const float* __restrict__ c3w,
                       const float* __restrict__ gamma, const float* __restrict__ var_,
                       unsigned short* __restrict__ Wall) {
    int idx = blockIdx.x * 256 + threadIdx.x;
    if (idx >= 16 * NWV) return;
    int v = idx / NWV, rem = idx % NWV;
    int tap  = rem >> 12;
    int w12  = rem & 4095;
    int ks   = w12 >> 10;
    int cf   = (w12 >> 9) & 1;
    int lane = (w12 >> 3) & 63;
    int j    = w12 & 7;
    int co = cf * 32 + (lane & 31);
    int ci = ks * 16 + (lane >> 5) * 8 + j;
    int ta = tap / 3, tb = tap % 3;
    const float* src; int k, srcci, l;
    if (v < 8)       { k = v & 3;  srcci = (ci + 8 * v) & 63; src = dcn_w; l = 0; }
    else if (v < 12) { k = v - 8;  srcci = ci; src = c2w; l = 1; }
    else             { k = v - 12; srcci = ci; src = c3w; l = 2; }
    int sa, sb; rotmap(k, ta, tb, sa, sb);
    float s = gamma[l * 64 + co] * rsqrtf(var_[l * 64 + co] + 1e-5f);
    Wall[idx] = f2bf(src[((co * 64 + srcci) * 3 + sa) * 3 + sb] * s);
}

__global__ void prep_bias(const float* __restrict__ dcn_b, const float* __restrict__ c2b,
                          const float* __restrict__ c3b,
                          const float* __restrict__ gamma, const float* __restrict__ beta,
                          const float* __restrict__ mean, const float* __restrict__ var_,
                          float* __restrict__ biasg) {
    int t = threadIdx.x;
    if (t < 192) {
        int l = t >> 6, c = t & 63;
        const float* cb = (l == 0) ? dcn_b : ((l == 1) ? c2b : c3b);
        float s = gamma[l * 64 + c] * rsqrtf(var_[l * 64 + c] + 1e-5f);
        biasg[t] = cb[c] * s + beta[l * 64 + c] - mean[l * 64 + c] * s;
    }
}

// NCHW fp32 -> NHWC bf16.
__global__ __launch_bounds__(256) void prep_x(const float* __restrict__ in,
                                              unsigned short* __restrict__ out) {
    __shared__ float row[64 * 97];
    int by = blockIdx.x;
    int b = by / 96, y = by % 96;
    int t = threadIdx.x;
    for (int e = t; e < 6144; e += 256) {
        int c = e / 96, x = e - c * 96;
        row[c * 97 + x] = in[(((size_t)(b * 64 + c) * 96 + y) * 96) + x];
    }
    __syncthreads();
    for (int e = t; e < 6144; e += 256) {
        int x = e >> 6, c = e & 63;
        out[(((size_t)(b * 96 + y) * 96 + x) << 6) + c] = f2bf(row[c * 97 + x]);
    }
}

// Zero the 4-wide border ring of even-branch 104x104 frames (odd frames are fully written).
__global__ __launch_bounds__(256) void border_clear(unsigned short* __restrict__ buf1) {
    int idx = blockIdx.y;                      // 0..31 -> even-branch z
    int br = (idx >> 3) * 2, b = idx & 7;
    int z = br * 8 + b;
    int i = blockIdx.x * 32 + (threadIdx.x >> 3);   // 0..1599 border pixels
    int g = threadIdx.x & 7;
    int r, c;
    if (i < 416)      { r = i / 104;              c = i % 104; }
    else if (i < 832) { int j = i - 416; r = 100 + j / 104; c = j % 104; }
    else              { int j = i - 832; r = 4 + (j >> 3); int c8 = j & 7;
                        c = (c8 < 4) ? c8 : 92 + c8; }
    uint4 zero = make_uint4(0u, 0u, 0u, 0u);
    *(uint4*)(buf1 + (size_t)z * (104 * 104 * 64) + ((size_t)(r * 104 + c) << 6) + (g << 3)) = zero;
}

// ---------------- conv1: all 8 branches -> framed buf1 (104x104, NHWC bf16) ----------------
// Block: 256 thr (4 waves). Tile: frame rows [fy0,fy0+8) x cols [fx0,fx0+32) x 64 co.
// x tile 10x34x64ci staged once (full K). Wave w: rows {2w,2w+1}. Reads:MFMA = 1:3.
// Epilogue transposes through LDS -> 1KB contiguous global stores.
__global__ __launch_bounds__(256, 2) void conv1_k(
    const unsigned short* __restrict__ xhwc, unsigned short* __restrict__ buf1,
    const unsigned short* __restrict__ Wall, const float* __restrict__ biasg) {

    __shared__ __align__(16) unsigned short xt[10 * 34 * 64];   // 43,520 B

    int z = blockIdx.z, br = z >> 3, b = z & 7, odd = br & 1;
    int fy0 = blockIdx.y * 8, fx0 = blockIdx.x * 32;
    int t = threadIdx.x, lane = t & 63, wv = t >> 6;
    int n = lane & 31, kq = lane >> 5;

    const unsigned short* xb = xhwc + ((size_t)b * 96 * 96 << 6);
    const short8* Ag = (const short8*)(Wall + (size_t)br * NWV);

    // stage x: tile rows fy0-5.. cols fx0-5.., zero OOB, key = tilecol&7
    for (int e = t; e < 2720; e += 256) {
        int p = e >> 3, g = e & 7;
        int yy = p / 34, xx = p - yy * 34;
        int gy = fy0 - 5 + yy, gx = fx0 - 5 + xx;
        uint4 v = make_uint4(0u, 0u, 0u, 0u);
        if ((unsigned)gy < 96u && (unsigned)gx < 96u)
            v = *(const uint4*)(xb + ((size_t)(gy * 96 + gx) << 6) + (g << 3));
        *(uint4*)(xt + (p << 6) + ((g ^ (xx & 7)) << 3)) = v;
    }
    __syncthreads();

    floatx16 acc[2][2];   // [cf][pf]
#pragma unroll
    for (int cf = 0; cf < 2; cf++)
#pragma unroll
        for (int pf = 0; pf < 2; pf++)
#pragma unroll
            for (int i = 0; i < 16; i++) acc[cf][pf][i] = 0.f;

#pragma unroll
    for (int ks = 0; ks < 4; ks++) {
#pragma unroll
        for (int tb = 0; tb < 3; tb++) {
            short8 a[3][2];
#pragma unroll
            for (int ta = 0; ta < 3; ta++)
#pragma unroll
                for (int cf = 0; cf < 2; cf++)
                    a[ta][cf] = Ag[(((ta * 3 + tb) * 4 + ks) * 2 + cf) * 64 + lane];
            int xx = n + tb;
            int g = ((ks * 2 + kq) ^ (xx & 7)) << 3;
            short8 bf[4];
#pragma unroll
            for (int rr = 0; rr < 4; rr++) {
                int p = (2 * wv + rr) * 34 + xx;
                bf[rr] = *(const short8*)(xt + (p << 6) + g);
            }
#pragma unroll
            for (int ta = 0; ta < 3; ta++)
#pragma unroll
                for (int pf = 0; pf < 2; pf++) {
                    int rr = pf + ta;
                    acc[0][pf] = __builtin_amdgcn_mfma_f32_32x32x16_bf16(a[ta][0], bf[rr], acc[0][pf], 0, 0, 0);
                    acc[1][pf] = __builtin_amdgcn_mfma_f32_32x32x16_bf16(a[ta][1], bf[rr], acc[1][pf], 0, 0, 0);
                }
        }
    }

    // bias (co0 = 4kq + 8rb + 32cf)
    float4 bv[2][4];
#pragma unroll
    for (int cf = 0; cf < 2; cf++)
#pragma unroll
        for (int rb = 0; rb < 4; rb++)
            bv[cf][rb] = *(const float4*)(biasg + 32 * cf + 8 * rb + 4 * kq);

    __syncthreads();   // xt reads done; reuse as transpose buffer (256 px * 128 B)
#pragma unroll
    for (int pf = 0; pf < 2; pf++) {
        int pq = (2 * wv + pf) * 32 + n;
        int key = (pq & 7) << 1;
#pragma unroll
        for (int cf = 0; cf < 2; cf++)
#pragma unroll
            for (int rb = 0; rb < 4; rb++) {
                int u = kq + 2 * rb + 8 * cf;
                float v0 = fmaxf(acc[cf][pf][rb * 4 + 0] + bv[cf][rb].x, 0.f);
                float v1 = fmaxf(acc[cf][pf][rb * 4 + 1] + bv[cf][rb].y, 0.f);
                float v2 = fmaxf(acc[cf][pf][rb * 4 + 2] + bv[cf][rb].z, 0.f);
                float v3 = fmaxf(acc[cf][pf][rb * 4 + 3] + bv[cf][rb].w, 0.f);
                uint2 pk = make_uint2((unsigned)f2bf(v0) | ((unsigned)f2bf(v1) << 16),
                                      (unsigned)f2bf(v2) | ((unsigned)f2bf(v3) << 16));
                *(uint2*)((char*)xt + pq * 128 + ((u ^ key) << 3)) = pk;
            }
    }
    __syncthreads();

    unsigned short* fb = buf1 + (size_t)z * (104 * 104 * 64);
    int lo = odd ? 0 : 4, hi = odd ? 104 : 100;
    for (int e = t; e < 2048; e += 256) {
        int px = e >> 3, g = e & 7;
        int key = (px & 7) << 1;
        uint4 v = *(const uint4*)((const char*)xt + px * 128 + (((2 * g) ^ key) << 3));
        int lr = px >> 5, nn = px & 31;
        int f = fy0 + lr, fc = fx0 + nn;
        if (f >= lo && f < hi && fc >= lo && fc < hi)
            *(uint4*)(fb + ((size_t)(f * 104 + fc) << 6) + (g << 3)) = v;
    }
}

// ---------------- fused conv2+conv3 -> maxbuf ----------------
// Block: 512 thr (8 waves). conv3-out tile 16x32 per (z). conv2-out 20x36x64 lives in LDS.
// Input: framed buf1, rows [oy0,+24) x cols [ox0,+40), NO bounds checks (parity-uniform).
// Two 32-ci stages; stage-1 register-prefetched during stage-0 compute.
__global__ __launch_bounds__(512, 2) void conv23_k(
    const unsigned short* __restrict__ buf1, float* __restrict__ maxb,
    const unsigned short* __restrict__ Wall, const float* __restrict__ biasg) {

    __shared__ __align__(16) unsigned short c2out[768 * 64];   // 98,304 B (720 px + pad)
    __shared__ __align__(16) unsigned short xs[960 * 32];      // 61,440 B (24x40 px, 32 ci)

    int z = blockIdx.z, br = z >> 3, odd = br & 1;
    int oy0 = blockIdx.y * 16, ox0 = blockIdx.x * 32;
    int t = threadIdx.x, lane = t & 63, wv = t >> 6;
    int n = lane & 31, kq = lane >> 5;

    const unsigned short* fb = buf1 + (size_t)z * (104 * 104 * 64);
    const short8* A2 = (const short8*)(Wall + (size_t)(8  + (br & 3)) * NWV);
    const short8* A3 = (const short8*)(Wall + (size_t)(12 + (br & 3)) * NWV);

    // ---- P1: stage ci 0..31 ----
    for (int e = t; e < 3840; e += 512) {
        int p = e >> 2, g = e & 3;
        int yy = p / 40, xx = p - yy * 40;
        uint4 v = *(const uint4*)(fb + ((size_t)((oy0 + yy) * 104 + ox0 + xx) << 6) + (g << 3));
        *(uint4*)(xs + (p << 5) + ((g ^ (xx & 3)) << 3)) = v;
    }
    __syncthreads();

    // prefetch ci 32..63 into registers (overlaps stage-0 compute)
    uint4 pfv[8];
#pragma unroll
    for (int k = 0; k < 8; k++) {
        int e = t + k * 512;
        if (e < 3840) {
            int p = e >> 2, g = e & 3;
            int yy = p / 40, xx = p - yy * 40;
            pfv[k] = *(const uint4*)(fb + ((size_t)((oy0 + yy) * 104 + ox0 + xx) << 6) + 32 + (g << 3));
        }
    }

    // per-wave conv2-out pixel coords (3 chunks of 32, q-linear over 20x36, clamped)
    int q_[3], row2_[3], col2_[3];
#pragma unroll
    for (int jj = 0; jj < 3; jj++) {
        int q = 96 * wv + 32 * jj + n;
        q_[jj] = q;
        int qc = (q < 720) ? q : 719;
        int r2 = qc / 36;
        row2_[jj] = r2;
        col2_[jj] = qc - 36 * r2;
    }

    floatx16 acc2[3][2];   // [jj][cf]
#pragma unroll
    for (int jj = 0; jj < 3; jj++)
#pragma unroll
        for (int cf = 0; cf < 2; cf++)
#pragma unroll
            for (int i = 0; i < 16; i++) acc2[jj][cf][i] = 0.f;

    // ---- conv2 K-halves ----
#pragma unroll
    for (int s = 0; s < 2; s++) {
        if (s == 1) {
            __syncthreads();
#pragma unroll
            for (int k = 0; k < 8; k++) {
                int e = t + k * 512;
                if (e < 3840) {
                    int p = e >> 2, g = e & 3;
                    int xx2 = p - (p / 40) * 40;
                    *(uint4*)(xs + (p << 5) + ((g ^ (xx2 & 3)) << 3)) = pfv[k];
                }
            }
            __syncthreads();
        }
#pragma unroll
        for (int kl = 0; kl < 2; kl++) {
            int ks = s * 2 + kl;
#pragma unroll
            for (int tb = 0; tb < 3; tb++) {
                short8 a[3][2];
#pragma unroll
                for (int ta = 0; ta < 3; ta++)
#pragma unroll
                    for (int cf = 0; cf < 2; cf++)
                        a[ta][cf] = A2[(((ta * 3 + tb) * 4 + ks) * 2 + cf) * 64 + lane];
#pragma unroll
                for (int jj = 0; jj < 3; jj++) {
                    int colx = col2_[jj] + 2 * tb;
                    int gsw = ((kl * 2 + kq) ^ (colx & 3)) << 3;
#pragma unroll
                    for (int ta = 0; ta < 3; ta++) {
                        int p = (row2_[jj] + 2 * ta) * 40 + colx;
                        short8 bfr = *(const short8*)(xs + (p << 5) + gsw);
                        acc2[jj][0] = __builtin_amdgcn_mfma_f32_32x32x16_bf16(a[ta][0], bfr, acc2[jj][0], 0, 0, 0);
                        acc2[jj][1] = __builtin_amdgcn_mfma_f32_32x32x16_bf16(a[ta][1], bfr, acc2[jj][1], 0, 0, 0);
                    }
                }
            }
        }
    }

    // ---- P3: conv2 epilogue -> c2out LDS (bias+relu, zero-mask even-parity borders) ----
    int rlo2 = (!odd && oy0 == 0)  ? 2  : 0;
    int rhi2 = (!odd && oy0 == 80) ? 18 : 20;
    int clo2 = (!odd && ox0 == 0)  ? 2  : 0;
    int chi2 = (!odd && ox0 == 64) ? 34 : 36;
    float4 bv2[2][4];
#pragma unroll
    for (int cf = 0; cf < 2; cf++)
#pragma unroll
        for (int rb = 0; rb < 4; rb++)
            bv2[cf][rb] = *(const float4*)(biasg + 64 + 32 * cf + 8 * rb + 4 * kq);

#pragma unroll
    for (int jj = 0; jj < 3; jj++) {
        if (q_[jj] < 720) {
            bool valid = (row2_[jj] >= rlo2) && (row2_[jj] < rhi2) &&
                         (col2_[jj] >= clo2) && (col2_[jj] < chi2);
            int key = col2_[jj] & 14;
#pragma unroll
            for (int cf = 0; cf < 2; cf++)
#pragma unroll
                for (int rb = 0; rb < 4; rb++) {
                    int u = kq + 2 * rb + 8 * cf;
                    float v0 = 0.f, v1 = 0.f, v2 = 0.f, v3 = 0.f;
                    if (valid) {
                        v0 = fmaxf(acc2[jj][cf][rb * 4 + 0] + bv2[cf][rb].x, 0.f);
                        v1 = fmaxf(acc2[jj][cf][rb * 4 + 1] + bv2[cf][rb].y, 0.f);
                        v2 = fmaxf(acc2[jj][cf][rb * 4 + 2] + bv2[cf][rb].z, 0.f);
                        v3 = fmaxf(acc2[jj][cf][rb * 4 + 3] + bv2[cf][rb].w, 0.f);
                    }
                    uint2 pk = make_uint2((unsigned)f2bf(v0) | ((unsigned)f2bf(v1) << 16),
                                          (unsigned)f2bf(v2) | ((unsigned)f2bf(v3) << 16));
                    *(uint2*)((char*)c2out + q_[jj] * 128 + ((u ^ key) << 3)) = pk;
                }
        }
    }
    __syncthreads();

    // ---- P4: conv3 from c2out; wave owns out rows {2wv, 2wv+1} x 32 cols ----
    int r0 = 2 * wv;
    floatx16 acc3[2][2];   // [cf][pf]
#pragma unroll
    for (int cf = 0; cf < 2; cf++)
#pragma unroll
        for (int pf = 0; pf < 2; pf++)
#pragma unroll
            for (int i = 0; i < 16; i++) acc3[cf][pf][i] = 0.f;

#pragma unroll
    for (int ks = 0; ks < 4; ks++) {
#pragma unroll
        for (int tb = 0; tb < 3; tb++) {
            short8 a[3][2];
#pragma unroll
            for (int ta = 0; ta < 3; ta++)
#pragma unroll
                for (int cf = 0; cf < 2; cf++)
                    a[ta][cf] = A3[(((ta * 3 + tb) * 4 + ks) * 2 + cf) * 64 + lane];
            int col = n + 2 * tb;
            int key = col & 14;
            int ublk = 2 * (ks * 2 + kq);
            short8 bf[6];
#pragma unroll
            for (int rr = 0; rr < 6; rr++) {
                int q = (r0 + rr) * 36 + col;
                bf[rr] = *(const short8*)((const char*)c2out + q * 128 + ((ublk ^ key) << 3));
            }
#pragma unroll
            for (int ta = 0; ta < 3; ta++)
#pragma unroll
                for (int pf = 0; pf < 2; pf++) {
                    int rr = pf + 2 * ta;
                    acc3[0][pf] = __builtin_amdgcn_mfma_f32_32x32x16_bf16(a[ta][0], bf[rr], acc3[0][pf], 0, 0, 0);
                    acc3[1][pf] = __builtin_amdgcn_mfma_f32_32x32x16_bf16(a[ta][1], bf[rr], acc3[1][pf], 0, 0, 0);
                }
        }
    }

    // epilogue: bias + relu + max over 64 co -> maxb
    float4 bv3[2][4];
#pragma unroll
    for (int cf = 0; cf < 2; cf++)
#pragma unroll
        for (int rb = 0; rb < 4; rb++)
            bv3[cf][rb] = *(const float4*)(biasg + 128 + 32 * cf + 8 * rb + 4 * kq);

#pragma unroll
    for (int pf = 0; pf < 2; pf++) {
        float m = 0.f;
#pragma unroll
        for (int cf = 0; cf < 2; cf++)
#pragma unroll
            for (int rb = 0; rb < 4; rb++) {
                m = fmaxf(m, acc3[cf][pf][rb * 4 + 0] + bv3[cf][rb].x);
                m = fmaxf(m, acc3[cf][pf][rb * 4 + 1] + bv3[cf][rb].y);
                m = fmaxf(m, acc3[cf][pf][rb * 4 + 2] + bv3[cf][rb].z);
                m = fmaxf(m, acc3[cf][pf][rb * 4 + 3] + bv3[cf][rb].w);
            }
        m = fmaxf(m, 0.f);
        m = fmaxf(m, __shfl_xor(m, 32, 64));
        if (lane < 32)
            maxb[((size_t)z * 96 + oy0 + r0 + pf) * 96 + ox0 + n] = m;
    }
}

__global__ void final_k(const float* __restrict__ maxb, float* __restrict__ out) {
    int i = blockIdx.x * 256 + threadIdx.x;
    if (i < B * HW * HW) {
        int b = i / 9216, yx = i - b * 9216;
        float m = 0.f;
#pragma unroll
        for (int br = 0; br < 8; br++)
            m = fmaxf(m, maxb[((size_t)(br * 8 + b)) * 9216 + yx]);
        float v = 1.f / (1.f + expf(-m));
        out[i] = fminf(fmaxf(v, 1e-4f), 1.f - 1e-4f);
    }
}

// ---------------- launch ----------------

extern "C" void kernel_launch(void* const* d_in, const int* in_sizes, int n_in,
                              void* d_out, int out_size, void* d_ws, size_t ws_size,
                              hipStream_t stream) {
    const float* x     = (const float*)d_in[0];
    const float* dcn_w = (const float*)d_in[2];
    const float* dcn_b = (const float*)d_in[3];
    const float* c2w   = (const float*)d_in[4];
    const float* c2b   = (const float*)d_in[5];
    const float* c3w   = (const float*)d_in[6];
    const float* c3b   = (const float*)d_in[7];
    const float* gamma = (const float*)d_in[8];
    const float* beta  = (const float*)d_in[9];
    const float* mean  = (const float*)d_in[10];
    const float* var_  = (const float*)d_in[11];

    char* ws = (char*)d_ws;
    unsigned short* Wall = (unsigned short*)ws;                       // 1.18 MB
    size_t off = (size_t)16 * NWV * 2;
    float* biasg = (float*)(ws + off);            off += 1024;
    float* maxb  = (float*)(ws + off);            off += (size_t)64 * 9216 * 4;        // 2.36 MB
    unsigned short* xhwc = (unsigned short*)(ws + off); off += (size_t)B * 9216 * 64 * 2;    // 9.4 MB
    unsigned short* buf1 = (unsigned short*)(ws + off);                                 // 88.6 MB framed

    prep_w<<<(16 * NWV + 255) / 256, 256, 0, stream>>>(dcn_w, c2w, c3w, gamma, var_, Wall);
    prep_bias<<<1, 256, 0, stream>>>(dcn_b, c2b, c3b, gamma, beta, mean, var_, biasg);
    prep_x<<<B * 96, 256, 0, stream>>>(x, xhwc);
    border_clear<<<dim3(50, 32), 256, 0, stream>>>(buf1);

    dim3 g1(4, 13, 64);
    conv1_k<<<g1, 256, 0, stream>>>(xhwc, buf1, Wall, biasg);

    dim3 g23(3, 6, 64);
    conv23_k<<<g23, 512, 0, stream>>>(buf1, maxb, Wall, biasg);

    final_k<<<(B * HW * HW + 255) / 256, 256, 0, stream>>>(maxb, (float*)d_out);
}